// Round 4
// baseline (153.985 us; speedup 1.0000x reference)
//
#include <hip/hip_runtime.h>
#include <hip/hip_bf16.h>
#include <cmath>

#define SEQ   168
#define NF    8
#define PRED  24
#define HID   8
#define KTOT  1344          // SEQ*NF = GEMM K (k = s*8+f == x row flat index)
#define NCH   21            // 1344/64 k-chunks
#define NCOLI 416           // image cols: 384 interleaved T/S + 8 gin + 8 h0 + 16 pad
#define CHB   (NCOLI * 128) // 53248 bytes per k-chunk (col-major rows of 128B)
#define PI_F  3.14159265358979323846f

// ---------------- workspace layout ----------------
#define WS_DW       0        // floats: 8*25 softmaxed decomp weights
#define WS_ROTC     256      // floats: 3*2*4*4 rot coeffs
#define WS_CGIN     512      // floats: 8 gin constants
#define WS_WT       1024     // floats: 168*640 composed weights, ends 108544
#define WS_IMG_BYTE 524288   // bytes: bf16 image 21*53248 = 1,118,208

typedef __attribute__((ext_vector_type(8))) short bf16x8;
typedef __attribute__((ext_vector_type(4))) float f32x4;

__device__ __forceinline__ float frcp(float x)  { return __builtin_amdgcn_rcpf(x); }
__device__ __forceinline__ float ftanh(float x) {
    float xc = fminf(fmaxf(x, -15.f), 15.f);
    float e  = __expf(2.f * xc);
    return (e - 1.f) * frcp(e + 1.f);
}
__device__ __forceinline__ float sigm(float x) { return frcp(1.f + __expf(-x)); }
__device__ __forceinline__ unsigned short f2bf(float f) {
    __hip_bfloat16 h = __float2bfloat16(f);
    return __builtin_bit_cast(unsigned short, h);
}
__device__ __forceinline__ unsigned pack2(float a, float b) {
    return (unsigned)f2bf(a) | ((unsigned)f2bf(b) << 16);
}

// ---------------- setup: softmax(dw) + rot coeffs + gin consts ----------------
__global__ void k_setup(const float* __restrict__ decomp_w,
                        const float* __restrict__ vr, const float* __restrict__ vu,
                        const float* __restrict__ vc,
                        const float* __restrict__ sc_w, const float* __restrict__ sc_b,
                        const float* __restrict__ ta_b,
                        float* __restrict__ dw, float* __restrict__ rotc,
                        float* __restrict__ cgin) {
    int t = threadIdx.x;
    if (t < 8) {
        const float* row = decomp_w + t * 25;
        float m = row[0];
        for (int k = 1; k < 25; ++k) m = fmaxf(m, row[k]);
        float e[25]; float sum = 0.f;
        for (int k = 0; k < 25; ++k) { e[k] = expf(row[k] - m); sum += e[k]; }
        float inv = 1.f / sum;
        for (int k = 0; k < 25; ++k) dw[t * 25 + k] = e[k] * inv;
    } else if (t >= 64 && t < 88) {
        int n = t - 64;
        int v = n / 8, rest = n % 8;
        const float* w = (v == 0 ? vr : (v == 1 ? vu : vc)) + rest * 3;
        float phi = w[0], th = w[1], om = w[2];
        float c = cosf(0.5f * th), s = sinf(0.5f * th);
        float ap = -0.5f * (phi + om);
        float am =  0.5f * (phi - om);
        float* o = rotc + n * 4;
        o[0] = cosf(ap) * c;
        o[1] = sinf(ap) * c;
        o[2] = cosf(am) * s;
        o[3] = sinf(am) * s;
    } else if (t >= 96 && t < 104) {
        int h = t - 96;
        float a = sc_b[h];
        for (int cc = 0; cc < 32; ++cc) {
            float s = 0.f;
            for (int f = 0; f < 8; ++f) s += sc_w[h * 256 + f * 32 + cc];
            a = fmaf(ta_b[cc], s, a);
        }
        cgin[h] = a;
    }
}

// ---------------- compose conv into projection weights (f32, verified r1-r3) ----------------
// Wt cols: 0-191 trend (p*8+f), 192-383 seasonal (192+p*8+f), 384-639 ctx ((48+cc)*8+f)
__global__ void k_compose(const float* __restrict__ dw,
                          const float* __restrict__ trend_w,
                          const float* __restrict__ seasonal_w,
                          const float* __restrict__ ta_w,
                          float* __restrict__ Wt) {
    int n = blockIdx.x * 256 + threadIdx.x;
    if (n >= SEQ * 640) return;
    int sx  = n / 640;
    int col = n % 640;
    int j = col >> 3;
    int f = col & 7;
    const float* dwf = dw + f * 25;
    const float* wsel;
    int isTrend = 0;
    if (j < 24)      { wsel = trend_w    + j        * SEQ; isTrend = 1; }
    else if (j < 48) { wsel = seasonal_w + (j - 24) * SEQ; }
    else             { wsel = ta_w       + (j - 48) * SEQ; }
    float acc = 0.f;
    if (sx == 0) {
        for (int s = 0; s <= 12; ++s) {
            float cw = 0.f;
            for (int k = 0; k <= 12 - s; ++k) cw += dwf[k];
            acc = fmaf(cw, wsel[s], acc);
        }
    } else if (sx == 167) {
        for (int s = 155; s < 168; ++s) {
            float cw = 0.f;
            for (int k = 179 - s; k < 25; ++k) cw += dwf[k];
            acc = fmaf(cw, wsel[s], acc);
        }
    } else {
        int lo = sx - 12; if (lo < 0) lo = 0;
        int hi = sx + 12; if (hi > 167) hi = 167;
        for (int s = lo; s <= hi; ++s) acc = fmaf(dwf[sx - s + 12], wsel[s], acc);
    }
    Wt[sx * 640 + col] = isTrend ? acc : (wsel[sx] - acc);
}

// ---------------- build pre-swizzled bf16 image [kc][416 col][64 k] ----------------
// col c < 384: output o=c>>1, ts=c&1 -> Wt col ts*192+o (gated f == o&7)
// c in [384,392): gin col h=c-384 (sc_w folded); [392,400): h0 col (lags, f==7); else 0
__global__ void k_img(const float* __restrict__ Wt, const float* __restrict__ sc_w,
                      const float* __restrict__ h0_w, unsigned char* __restrict__ imgb) {
    int idx = blockIdx.x * 256 + threadIdx.x;   // 21*416*64 = 559104
    if (idx >= NCH * NCOLI * 64) return;
    int koff = idx & 63;
    int rest = idx >> 6;
    int c    = rest % NCOLI;
    int kc   = rest / NCOLI;
    int k = kc * 64 + koff;
    int s = k >> 3, f = k & 7;
    float val = 0.f;
    if (c < 384) {
        int o = c >> 1;
        if ((o & 7) == f) val = Wt[s * 640 + (c & 1) * 192 + o];
    } else if (c < 392) {
        int h = c - 384;
        float a = 0.f;
        for (int cc = 0; cc < 32; ++cc)
            a = fmaf(sc_w[h * 256 + f * 32 + cc], Wt[s * 640 + 384 + cc * 8 + f], a);
        val = a;
    } else if (c < 400) {
        if (f == 7) {
            const int LIDX[11] = {167,166,165,164,163,162,145,144,143,1,0};
            #pragma unroll
            for (int i = 0; i < 11; ++i)
                if (s == LIDX[i]) val = h0_w[(c - 392) * 11 + i];
        }
    }
    int byte = (c * 128 + koff * 2) ^ ((c & 7) << 4);
    *(unsigned short*)(imgb + (size_t)kc * CHB + byte) = f2bf(val);
}

// ---------------- VQC: 16 lanes hold the 16 complex amplitudes (verified) ----------------
__device__ __forceinline__ float shflg(float v, int grp, int idx) {
    return __shfl(v, grp + idx, 64);
}

__device__ void vqc_run(const float cq[4], const float sq[4],
                        const float* __restrict__ rc,
                        int l, int grp, float exps[4]) {
    float re = (l == 0) ? 1.f : 0.f;
    float im = 0.f;
    #pragma unroll
    for (int layer = 0; layer < 2; ++layer) {
        #pragma unroll
        for (int q = 0; q < 4; ++q) {
            int m = 1 << (3 - q);
            float pre = shflg(re, grp, l ^ m);
            float pim = shflg(im, grp, l ^ m);
            float sg = (l & m) ? sq[q] : -sq[q];
            re = cq[q] * re + sg * pre;
            im = cq[q] * im + sg * pim;
        }
        #pragma unroll
        for (int q = 0; q < 4; ++q) {
            int m = 1 << (3 - q);
            const float* g = rc + (layer * 4 + q) * 4;
            float A = g[0], B = g[1], C = g[2], D = g[3];
            float pre = shflg(re, grp, l ^ m);
            float pim = shflg(im, grp, l ^ m);
            float car, cai, cpr, cpi;
            if (l & m) { car = A; cai = -B; cpr =  C; cpi = -D; }
            else       { car = A; cai =  B; cpr = -C; cpi = -D; }
            float nre = car * re - cai * im + cpr * pre - cpi * pim;
            float nim = car * im + cai * re + cpr * pim + cpi * pre;
            re = nre; im = nim;
        }
        #pragma unroll
        for (int q = 0; q < 4; ++q) {
            int mc = 1 << (3 - q);
            int mt = 1 << (3 - ((q + 1) & 3));
            float pre = shflg(re, grp, l ^ mt);
            float pim = shflg(im, grp, l ^ mt);
            if (l & mc) { re = pre; im = pim; }
        }
    }
    float prob = re * re + im * im;
    float v0 = (l & 8) ? -prob : prob;
    float v1 = (l & 4) ? -prob : prob;
    float v2 = (l & 2) ? -prob : prob;
    float v3 = (l & 1) ? -prob : prob;
    #pragma unroll
    for (int m = 1; m < 16; m <<= 1) {
        v0 += __shfl_xor(v0, m, 64);
        v1 += __shfl_xor(v1, m, 64);
        v2 += __shfl_xor(v2, m, 64);
        v3 += __shfl_xor(v3, m, 64);
    }
    exps[0] = v0; exps[1] = v1; exps[2] = v2; exps[3] = v3;
}

// ---------------- mega-fused: GEMM (x once) + VQC + fusion + store ----------------
// M-tile 64, N 416; 4 waves = 2(M: wm*32 rows) x 2(N: wn*208 cols); BK=64, 21 chunks.
__global__ __launch_bounds__(256, 2)
void k_fused(const float* __restrict__ x, const unsigned char* __restrict__ img,
             const float* __restrict__ rotc, const float* __restrict__ cgin,
             const float* __restrict__ h0_b,
             const float* __restrict__ crz_w, const float* __restrict__ crz_b,
             const float* __restrict__ cn_w, const float* __restrict__ cn_b,
             const float* __restrict__ expand_w, const float* __restrict__ expand_b,
             const float* __restrict__ mod_w, const float* __restrict__ mod_b,
             const float* __restrict__ trend_b, const float* __restrict__ seasonal_b,
             const float* __restrict__ fusion_alpha,
             float* __restrict__ out, int Btot)
{
    __shared__ uint4 ldsq[3840];                        // 61440 B
    unsigned char* Asb = (unsigned char*)ldsq;          // [0, 8192): 64 rows x 64 k bf16, swz
    unsigned char* Bsb = (unsigned char*)ldsq + 8192;   // [8192, 61440): 416 x 64 k bf16, swz
    float* ghbuf = (float*)ldsq;                        // epi overlay: 64*17 f32 = 4352 B
    float* modt  = (float*)((unsigned char*)ldsq + 8192); // epi overlay: 64*25 f32 = 6400 B

    const int t    = threadIdx.x;
    const int b0   = blockIdx.x * 64;
    const int w    = t >> 6, lane = t & 63, lr = lane & 15, lg = lane >> 4;
    const int wm   = w & 1, wn = w >> 1;
    const int cb   = wn * 208;

    f32x4 acc0[13], acc1[13];
    #pragma unroll
    for (int j = 0; j < 13; ++j) {
        acc0[j] = (f32x4){0.f, 0.f, 0.f, 0.f};
        acc1[j] = (f32x4){0.f, 0.f, 0.f, 0.f};
    }

    // staging maps: A: thread covers row (t>>2), floats [acol*16, +16); B: linear 13 uint4
    const int arow = t >> 2, acol = t & 3;
    int gr = b0 + arow; if (gr >= Btot) gr = Btot - 1;
    const float* xp = x + (size_t)gr * KTOT + acol * 16;
    const unsigned char* imgp = img + (size_t)t * 16;

    float4 ra[4]; uint4 rb[13];
    #pragma unroll
    for (int u = 0; u < 4; ++u) ra[u] = *(const float4*)&xp[u * 4];
    #pragma unroll
    for (int i = 0; i < 13; ++i) rb[i] = *(const uint4*)&imgp[i * 4096];

    for (int kc = 0; kc < NCH; ++kc) {
        __syncthreads();                       // readers of previous tile done
        // publish staged regs (implicit vmcnt waits; loads had full compute window)
        #pragma unroll
        for (int v = 0; v < 2; ++v) {
            uint4 pk;
            float4 a0 = ra[2 * v], a1 = ra[2 * v + 1];
            pk.x = pack2(a0.x, a0.y); pk.y = pack2(a0.z, a0.w);
            pk.z = pack2(a1.x, a1.y); pk.w = pack2(a1.z, a1.w);
            int byte = (arow * 128 + acol * 32 + v * 16) ^ ((arow & 7) << 4);
            *(uint4*)&Asb[byte] = pk;
        }
        #pragma unroll
        for (int i = 0; i < 13; ++i)
            *(uint4*)&Bsb[(t + i * 256) * 16] = rb[i];
        __syncthreads();                       // tile visible
        if (kc + 1 < NCH) {                    // issue next-tile loads under the MFMA window
            #pragma unroll
            for (int u = 0; u < 4; ++u)
                ra[u] = *(const float4*)&xp[(kc + 1) * 64 + u * 4];
            #pragma unroll
            for (int i = 0; i < 13; ++i)
                rb[i] = *(const uint4*)&imgp[(size_t)(kc + 1) * CHB + i * 4096];
        }
        #pragma unroll
        for (int kk = 0; kk < 2; ++kk) {
            bf16x8 af0, af1;
            {
                int m = wm * 32 + lr;
                af0 = *(const bf16x8*)&Asb[(m * 128 + kk * 64 + lg * 16) ^ ((m & 7) << 4)];
            }
            {
                int m = wm * 32 + 16 + lr;
                af1 = *(const bf16x8*)&Asb[(m * 128 + kk * 64 + lg * 16) ^ ((m & 7) << 4)];
            }
            #pragma unroll
            for (int j = 0; j < 13; ++j) {
                int c = cb + j * 16 + lr;
                bf16x8 bv = *(const bf16x8*)&Bsb[(c * 128 + kk * 64 + lg * 16) ^ ((c & 7) << 4)];
                acc0[j] = __builtin_amdgcn_mfma_f32_16x16x32_bf16(af0, bv, acc0[j], 0, 0, 0);
                acc1[j] = __builtin_amdgcn_mfma_f32_16x16x32_bf16(af1, bv, acc1[j], 0, 0, 0);
            }
        }
    }
    __syncthreads();

    // ---- phase 1: wn==1 waves publish gin/h0 frag (cols 384-399, local j=11) ----
    if (wn == 1) {
        #pragma unroll
        for (int reg = 0; reg < 4; ++reg) {
            ghbuf[(wm * 32      + lg * 4 + reg) * 17 + lr] = acc0[11][reg];
            ghbuf[(wm * 32 + 16 + lg * 4 + reg) * 17 + lr] = acc1[11][reg];
        }
    }
    __syncthreads();

    // ---- phase 2: VQC chain for 64 rows (16 lanes/row, 4 passes) ----
    {
        const int gidx = t >> 4;
        const int l    = t & 15;
        const int grp  = lane & 48;
        #pragma unroll 1
        for (int p2 = 0; p2 < 4; ++p2) {
            int rl = p2 * 16 + gidx;
            float gin[HID], h0v[HID];
            #pragma unroll
            for (int h = 0; h < HID; ++h) {
                gin[h] = ftanh(ghbuf[rl * 17 + h]     + cgin[h]);
                h0v[h] = ftanh(ghbuf[rl * 17 + 8 + h] + h0_b[h]);
            }
            float rz[4];
            #pragma unroll
            for (int q = 0; q < 4; ++q) {
                float a = crz_b[q];
                #pragma unroll
                for (int k = 0; k < 8; ++k) a = fmaf(gin[k], crz_w[q * 16 + k], a);
                #pragma unroll
                for (int k = 0; k < 8; ++k) a = fmaf(h0v[k], crz_w[q * 16 + 8 + k], a);
                rz[q] = ftanh(a) * PI_F;
            }
            float cq[4], sq[4];
            #pragma unroll
            for (int q = 0; q < 4; ++q) { cq[q] = __cosf(0.5f * rz[q]); sq[q] = __sinf(0.5f * rz[q]); }

            float er[4], ez[4];
            vqc_run(cq, sq, rotc + 0 * 32, l, grp, er);
            vqc_run(cq, sq, rotc + 1 * 32, l, grp, ez);

            float rr[HID], zz[HID];
            #pragma unroll
            for (int h = 0; h < HID; ++h) {
                float a = expand_b[h], b = expand_b[h];
                #pragma unroll
                for (int q = 0; q < 4; ++q) {
                    a = fmaf(er[q], expand_w[h * 4 + q], a);
                    b = fmaf(ez[q], expand_w[h * 4 + q], b);
                }
                rr[h] = sigm(a);
                zz[h] = sigm(b);
            }
            float ni[4];
            #pragma unroll
            for (int q = 0; q < 4; ++q) {
                float a = cn_b[q];
                #pragma unroll
                for (int k = 0; k < 8; ++k) a = fmaf(rr[k] * h0v[k], cn_w[q * 16 + k], a);
                #pragma unroll
                for (int k = 0; k < 8; ++k) a = fmaf(gin[k], cn_w[q * 16 + 8 + k], a);
                ni[q] = ftanh(a) * PI_F;
            }
            #pragma unroll
            for (int q = 0; q < 4; ++q) { cq[q] = __cosf(0.5f * ni[q]); sq[q] = __sinf(0.5f * ni[q]); }
            float en[4];
            vqc_run(cq, sq, rotc + 2 * 32, l, grp, en);

            float hn[HID];
            #pragma unroll
            for (int h = 0; h < HID; ++h) {
                float a = expand_b[h];
                #pragma unroll
                for (int q = 0; q < 4; ++q) a = fmaf(en[q], expand_w[h * 4 + q], a);
                float nn = ftanh(a);
                hn[h] = (1.f - zz[h]) * nn + zz[h] * h0v[h];
            }
            int pp = l;
            float a = mod_b[pp];
            #pragma unroll
            for (int h = 0; h < HID; ++h) a = fmaf(hn[h], mod_w[pp * 8 + h], a);
            modt[rl * 25 + pp] = ftanh(a);
            if (l < 8) {
                pp = l + 16;
                a = mod_b[pp];
                #pragma unroll
                for (int h = 0; h < HID; ++h) a = fmaf(hn[h], mod_w[pp * 8 + h], a);
                modt[rl * 25 + pp] = ftanh(a);
            }
        }
    }
    __syncthreads();

    // ---- phase 3: fuse interleaved T/S pairs with modulation, store ----
    const float alpha = sigm(fusion_alpha[0]);
    #pragma unroll
    for (int j = 0; j < 13; ++j) {
        int cbase = cb + j * 16;
        if (cbase >= 384) continue;            // gin/h0/pad frags
        int p = cbase >> 4;                    // output p index, uniform per frag
        float tb = trend_b[p], sb = seasonal_b[p];
        #pragma unroll
        for (int mf = 0; mf < 2; ++mf) {
            #pragma unroll
            for (int reg = 0; reg < 4; ++reg) {
                int rl = wm * 32 + mf * 16 + lg * 4 + reg;
                float v  = mf ? acc1[j][reg] : acc0[j][reg];
                float pt = __shfl_xor(v, 1, 64);
                float md = modt[rl * 25 + p];
                if (!(lr & 1)) {               // even lane holds T, partner holds S
                    int R = b0 + rl;
                    if (R < Btot) {
                        float res = alpha * ((pt + sb) * (1.f + md)) + (1.f - alpha) * (v + tb);
                        out[(size_t)R * 192 + (cbase >> 1) + (lr >> 1)] = res;
                    }
                }
            }
        }
    }
}

extern "C" void kernel_launch(void* const* d_in, const int* in_sizes, int n_in,
                              void* d_out, int out_size, void* d_ws, size_t ws_size,
                              hipStream_t stream) {
    const float* x          = (const float*)d_in[0];
    const float* decomp_w   = (const float*)d_in[1];
    const float* trend_w    = (const float*)d_in[2];
    const float* trend_b    = (const float*)d_in[3];
    const float* seasonal_w = (const float*)d_in[4];
    const float* seasonal_b = (const float*)d_in[5];
    const float* h0_w       = (const float*)d_in[6];
    const float* h0_b       = (const float*)d_in[7];
    const float* ta_w       = (const float*)d_in[8];
    const float* ta_b       = (const float*)d_in[9];
    const float* sc_w       = (const float*)d_in[10];
    const float* sc_b       = (const float*)d_in[11];
    const float* crz_w      = (const float*)d_in[12];
    const float* crz_b      = (const float*)d_in[13];
    const float* cn_w       = (const float*)d_in[14];
    const float* cn_b       = (const float*)d_in[15];
    const float* vqc_r      = (const float*)d_in[16];
    const float* vqc_u      = (const float*)d_in[17];
    const float* vqc_c      = (const float*)d_in[18];
    const float* expand_w   = (const float*)d_in[19];
    const float* expand_b   = (const float*)d_in[20];
    const float* mod_w      = (const float*)d_in[21];
    const float* mod_b      = (const float*)d_in[22];
    const float* fus_a      = (const float*)d_in[23];
    float* out = (float*)d_out;

    float* ws   = (float*)d_ws;
    float* dw   = ws + WS_DW;
    float* rotc = ws + WS_ROTC;
    float* cgin = ws + WS_CGIN;
    float* Wt   = ws + WS_WT;
    unsigned char* img = (unsigned char*)d_ws + WS_IMG_BYTE;

    const int Btot = in_sizes[0] / (SEQ * NF);

    k_setup<<<1, 256, 0, stream>>>(decomp_w, vqc_r, vqc_u, vqc_c, sc_w, sc_b, ta_b,
                                   dw, rotc, cgin);
    k_compose<<<(SEQ * 640 + 255) / 256, 256, 0, stream>>>(dw, trend_w, seasonal_w, ta_w, Wt);
    k_img<<<(NCH * NCOLI * 64 + 255) / 256, 256, 0, stream>>>(Wt, sc_w, h0_w, img);

    k_fused<<<(Btot + 63) / 64, 256, 0, stream>>>(x, img, rotc, cgin, h0_b,
                                                  crz_w, crz_b, cn_w, cn_b,
                                                  expand_w, expand_b, mod_w, mod_b,
                                                  trend_b, seasonal_b, fus_a, out, Btot);
}

// Round 5
// 78.904 us; speedup vs baseline: 1.9516x; 1.9516x over previous
//
#include <hip/hip_runtime.h>
#include <hip/hip_bf16.h>
#include <cmath>

#define SEQ   168
#define NF    8
#define PRED  24
#define HID   8
#define KTOT  1344          // SEQ*NF = GEMM K (k = s*8+f == x row flat index)
#define NCH   21            // 1344/64 k-chunks
#define NCOLI 448           // image cols: 384 interleaved T/S + 8 gin + 8 h0 + 48 pad
#define CHB   (NCOLI * 128) // 57344 bytes per k-chunk (col rows of 128B, XOR-swizzled)
#define PI_F  3.14159265358979323846f

// ---------------- workspace layout ----------------
#define WS_DW       0        // floats: 8*25 softmaxed decomp weights
#define WS_ROTC     256      // floats: 3*2*4*4 rot coeffs
#define WS_CGIN     512      // floats: 8 gin constants
#define WS_WT       1024     // floats: 168*640 composed weights, ends 108544
#define WS_IMG_BYTE 524288   // bytes: bf16 image 21*57344 = 1,204,224

typedef __attribute__((ext_vector_type(8))) short bf16x8;
typedef __attribute__((ext_vector_type(4))) float f32x4;

__device__ __forceinline__ float frcp(float x)  { return __builtin_amdgcn_rcpf(x); }
__device__ __forceinline__ float ftanh(float x) {
    float xc = fminf(fmaxf(x, -15.f), 15.f);
    float e  = __expf(2.f * xc);
    return (e - 1.f) * frcp(e + 1.f);
}
__device__ __forceinline__ float sigm(float x) { return frcp(1.f + __expf(-x)); }
__device__ __forceinline__ unsigned short f2bf(float f) {
    __hip_bfloat16 h = __float2bfloat16(f);
    return __builtin_bit_cast(unsigned short, h);
}
__device__ __forceinline__ unsigned pack2(float a, float b) {
    return (unsigned)f2bf(a) | ((unsigned)f2bf(b) << 16);
}
// async global->LDS, 16B per lane; lds dest = wave-uniform base + lane*16
__device__ __forceinline__ void gload16(const void* g, void* l) {
    __builtin_amdgcn_global_load_lds(
        (const __attribute__((address_space(1))) unsigned int*)g,
        (__attribute__((address_space(3))) unsigned int*)l, 16, 0, 0);
}

// ---------------- setup: softmax(dw) + rot coeffs + gin consts ----------------
__global__ void k_setup(const float* __restrict__ decomp_w,
                        const float* __restrict__ vr, const float* __restrict__ vu,
                        const float* __restrict__ vc,
                        const float* __restrict__ sc_w, const float* __restrict__ sc_b,
                        const float* __restrict__ ta_b,
                        float* __restrict__ dw, float* __restrict__ rotc,
                        float* __restrict__ cgin) {
    int t = threadIdx.x;
    if (t < 8) {
        const float* row = decomp_w + t * 25;
        float m = row[0];
        for (int k = 1; k < 25; ++k) m = fmaxf(m, row[k]);
        float e[25]; float sum = 0.f;
        for (int k = 0; k < 25; ++k) { e[k] = expf(row[k] - m); sum += e[k]; }
        float inv = 1.f / sum;
        for (int k = 0; k < 25; ++k) dw[t * 25 + k] = e[k] * inv;
    } else if (t >= 64 && t < 88) {
        int n = t - 64;
        int v = n / 8, rest = n % 8;
        const float* w = (v == 0 ? vr : (v == 1 ? vu : vc)) + rest * 3;
        float phi = w[0], th = w[1], om = w[2];
        float c = cosf(0.5f * th), s = sinf(0.5f * th);
        float ap = -0.5f * (phi + om);
        float am =  0.5f * (phi - om);
        float* o = rotc + n * 4;
        o[0] = cosf(ap) * c;
        o[1] = sinf(ap) * c;
        o[2] = cosf(am) * s;
        o[3] = sinf(am) * s;
    } else if (t >= 96 && t < 104) {
        int h = t - 96;
        float a = sc_b[h];
        for (int cc = 0; cc < 32; ++cc) {
            float s = 0.f;
            for (int f = 0; f < 8; ++f) s += sc_w[h * 256 + f * 32 + cc];
            a = fmaf(ta_b[cc], s, a);
        }
        cgin[h] = a;
    }
}

// ---------------- compose conv into projection weights (f32, verified r1-r4) ----------------
__global__ void k_compose(const float* __restrict__ dw,
                          const float* __restrict__ trend_w,
                          const float* __restrict__ seasonal_w,
                          const float* __restrict__ ta_w,
                          float* __restrict__ Wt) {
    int n = blockIdx.x * 256 + threadIdx.x;
    if (n >= SEQ * 640) return;
    int sx  = n / 640;
    int col = n % 640;
    int j = col >> 3;
    int f = col & 7;
    const float* dwf = dw + f * 25;
    const float* wsel;
    int isTrend = 0;
    if (j < 24)      { wsel = trend_w    + j        * SEQ; isTrend = 1; }
    else if (j < 48) { wsel = seasonal_w + (j - 24) * SEQ; }
    else             { wsel = ta_w       + (j - 48) * SEQ; }
    float acc = 0.f;
    if (sx == 0) {
        for (int s = 0; s <= 12; ++s) {
            float cw = 0.f;
            for (int k = 0; k <= 12 - s; ++k) cw += dwf[k];
            acc = fmaf(cw, wsel[s], acc);
        }
    } else if (sx == 167) {
        for (int s = 155; s < 168; ++s) {
            float cw = 0.f;
            for (int k = 179 - s; k < 25; ++k) cw += dwf[k];
            acc = fmaf(cw, wsel[s], acc);
        }
    } else {
        int lo = sx - 12; if (lo < 0) lo = 0;
        int hi = sx + 12; if (hi > 167) hi = 167;
        for (int s = lo; s <= hi; ++s) acc = fmaf(dwf[sx - s + 12], wsel[s], acc);
    }
    Wt[sx * 640 + col] = isTrend ? acc : (wsel[sx] - acc);
}

// ---------------- build pre-swizzled bf16 image [kc][448 col][64 k] ----------------
// col c < 384: output o=c>>1, ts=c&1 -> Wt col ts*192+o (gated f == o&7)
// c in [384,392): gin col (sc_w folded); [392,400): h0 col (lags, f==7); else 0
__global__ void k_img(const float* __restrict__ Wt, const float* __restrict__ sc_w,
                      const float* __restrict__ h0_w, unsigned char* __restrict__ imgb) {
    int idx = blockIdx.x * 256 + threadIdx.x;   // 21*448*64 = 602112
    if (idx >= NCH * NCOLI * 64) return;
    int koff = idx & 63;
    int rest = idx >> 6;
    int c    = rest % NCOLI;
    int kc   = rest / NCOLI;
    int k = kc * 64 + koff;
    int s = k >> 3, f = k & 7;
    float val = 0.f;
    if (c < 384) {
        int o = c >> 1;
        if ((o & 7) == f) val = Wt[s * 640 + (c & 1) * 192 + o];
    } else if (c < 392) {
        int h = c - 384;
        float a = 0.f;
        for (int cc = 0; cc < 32; ++cc)
            a = fmaf(sc_w[h * 256 + f * 32 + cc], Wt[s * 640 + 384 + cc * 8 + f], a);
        val = a;
    } else if (c < 400) {
        if (f == 7) {
            const int LIDX[11] = {167,166,165,164,163,162,145,144,143,1,0};
            #pragma unroll
            for (int i = 0; i < 11; ++i)
                if (s == LIDX[i]) val = h0_w[(c - 392) * 11 + i];
        }
    }
    int byte = (c * 128 + koff * 2) ^ ((c & 7) << 4);
    *(unsigned short*)(imgb + (size_t)kc * CHB + byte) = f2bf(val);
}

// ---------------- VQC: 16 lanes hold the 16 complex amplitudes (verified) ----------------
__device__ __forceinline__ float shflg(float v, int grp, int idx) {
    return __shfl(v, grp + idx, 64);
}

__device__ void vqc_run(const float cq[4], const float sq[4],
                        const float* __restrict__ rc,
                        int l, int grp, float exps[4]) {
    float re = (l == 0) ? 1.f : 0.f;
    float im = 0.f;
    #pragma unroll
    for (int layer = 0; layer < 2; ++layer) {
        #pragma unroll
        for (int q = 0; q < 4; ++q) {
            int m = 1 << (3 - q);
            float pre = shflg(re, grp, l ^ m);
            float pim = shflg(im, grp, l ^ m);
            float sg = (l & m) ? sq[q] : -sq[q];
            re = cq[q] * re + sg * pre;
            im = cq[q] * im + sg * pim;
        }
        #pragma unroll
        for (int q = 0; q < 4; ++q) {
            int m = 1 << (3 - q);
            const float* g = rc + (layer * 4 + q) * 4;
            float A = g[0], B = g[1], C = g[2], D = g[3];
            float pre = shflg(re, grp, l ^ m);
            float pim = shflg(im, grp, l ^ m);
            float car, cai, cpr, cpi;
            if (l & m) { car = A; cai = -B; cpr =  C; cpi = -D; }
            else       { car = A; cai =  B; cpr = -C; cpi = -D; }
            float nre = car * re - cai * im + cpr * pre - cpi * pim;
            float nim = car * im + cai * re + cpr * pim + cpi * pre;
            re = nre; im = nim;
        }
        #pragma unroll
        for (int q = 0; q < 4; ++q) {
            int mc = 1 << (3 - q);
            int mt = 1 << (3 - ((q + 1) & 3));
            float pre = shflg(re, grp, l ^ mt);
            float pim = shflg(im, grp, l ^ mt);
            if (l & mc) { re = pre; im = pim; }
        }
    }
    float prob = re * re + im * im;
    float v0 = (l & 8) ? -prob : prob;
    float v1 = (l & 4) ? -prob : prob;
    float v2 = (l & 2) ? -prob : prob;
    float v3 = (l & 1) ? -prob : prob;
    #pragma unroll
    for (int m = 1; m < 16; m <<= 1) {
        v0 += __shfl_xor(v0, m, 64);
        v1 += __shfl_xor(v1, m, 64);
        v2 += __shfl_xor(v2, m, 64);
        v3 += __shfl_xor(v3, m, 64);
    }
    exps[0] = v0; exps[1] = v1; exps[2] = v2; exps[3] = v3;
}

// ---------------- mega-fused: GEMM (x once) + VQC + fusion + store ----------------
// M-tile 64, N 448; 8 waves = 2(M: wm) x 4(N: wn, strided frags fi = wn+4j); BK=64.
__global__ __launch_bounds__(512, 2)
void k_fused(const float* __restrict__ x, const unsigned char* __restrict__ img,
             const float* __restrict__ rotc, const float* __restrict__ cgin,
             const float* __restrict__ h0_b,
             const float* __restrict__ crz_w, const float* __restrict__ crz_b,
             const float* __restrict__ cn_w, const float* __restrict__ cn_b,
             const float* __restrict__ expand_w, const float* __restrict__ expand_b,
             const float* __restrict__ mod_w, const float* __restrict__ mod_b,
             const float* __restrict__ trend_b, const float* __restrict__ seasonal_b,
             const float* __restrict__ fusion_alpha,
             float* __restrict__ out, int Btot)
{
    __shared__ unsigned char lds[65536];
    unsigned char* Asb = lds;            // [0, 8192): 64 rows x 64 k bf16, XOR-swizzled
    unsigned char* Bsb = lds + 8192;     // [8192, 65536): 448 cols x 64 k bf16, swizzled
    float* ghbuf = (float*)lds;          // epi overlay: 64*17 f32 = 4352 B (over Asb)
    float* modt  = (float*)(lds + 8192); // epi overlay: 64*25 f32 = 6400 B (over Bsb)

    const int t    = threadIdx.x;
    const int b0   = blockIdx.x * 64;
    const int w    = t >> 6, lane = t & 63, lr = lane & 15, lg = lane >> 4;
    const int wm   = w & 1, wn = w >> 1;

    f32x4 acc0[7], acc1[7];
    #pragma unroll
    for (int j = 0; j < 7; ++j) {
        acc0[j] = (f32x4){0.f, 0.f, 0.f, 0.f};
        acc1[j] = (f32x4){0.f, 0.f, 0.f, 0.f};
    }

    // A staging map: thread covers row (t>>3), floats [acolq*8, +8)
    const int arow = t >> 3, acolq = t & 7;
    int gr = b0 + arow; if (gr >= Btot) gr = Btot - 1;
    const float* xp = x + (size_t)gr * KTOT + acolq * 8;

    float4 ra0 = *(const float4*)&xp[0];
    float4 ra1 = *(const float4*)&xp[4];

    for (int kc = 0; kc < NCH; ++kc) {
        __syncthreads();                       // prev tile fully consumed
        // publish A (regs -> bf16 LDS, swizzled)
        {
            uint4 pk;
            pk.x = pack2(ra0.x, ra0.y); pk.y = pack2(ra0.z, ra0.w);
            pk.z = pack2(ra1.x, ra1.y); pk.w = pack2(ra1.z, ra1.w);
            *(uint4*)&Asb[(arow * 128 + acolq * 16) ^ ((arow & 7) << 4)] = pk;
        }
        // B: async DMA this chunk into LDS (linear copy; image pre-swizzled)
        {
            const unsigned char* bsrc = img + (size_t)kc * CHB + w * 1024 + lane * 16;
            unsigned char* bdst = Bsb + w * 1024;
            #pragma unroll
            for (int i = 0; i < 7; ++i)
                gload16(bsrc + i * 8192, bdst + i * 8192);
        }
        __syncthreads();                       // drains DMA + ds_writes; tile visible
        // A prefetch for next chunk (lands during MFMA window + B DMA of next iter)
        if (kc + 1 < NCH) {
            ra0 = *(const float4*)&xp[(kc + 1) * 64];
            ra1 = *(const float4*)&xp[(kc + 1) * 64 + 4];
        }
        #pragma unroll
        for (int kk = 0; kk < 2; ++kk) {
            bf16x8 af0, af1;
            {
                int m = wm * 32 + lr;
                af0 = *(const bf16x8*)&Asb[(m * 128 + kk * 64 + lg * 16) ^ ((m & 7) << 4)];
            }
            {
                int m = wm * 32 + 16 + lr;
                af1 = *(const bf16x8*)&Asb[(m * 128 + kk * 64 + lg * 16) ^ ((m & 7) << 4)];
            }
            #pragma unroll
            for (int j = 0; j < 7; ++j) {
                int fi = wn + j * 4;
                if (fi < 25) {                 // 24 T/S frags + gin/h0 frag; skip pad
                    int c = fi * 16 + lr;
                    bf16x8 bv = *(const bf16x8*)&Bsb[(c * 128 + kk * 64 + lg * 16) ^ ((c & 7) << 4)];
                    acc0[j] = __builtin_amdgcn_mfma_f32_16x16x32_bf16(af0, bv, acc0[j], 0, 0, 0);
                    acc1[j] = __builtin_amdgcn_mfma_f32_16x16x32_bf16(af1, bv, acc1[j], 0, 0, 0);
                }
            }
        }
    }
    __syncthreads();

    // ---- phase 1: wn==0 waves publish gin/h0 frag (fi=24, j=6) ----
    if (wn == 0) {
        #pragma unroll
        for (int reg = 0; reg < 4; ++reg) {
            ghbuf[(wm * 32      + lg * 4 + reg) * 17 + lr] = acc0[6][reg];
            ghbuf[(wm * 32 + 16 + lg * 4 + reg) * 17 + lr] = acc1[6][reg];
        }
    }
    __syncthreads();

    // ---- phase 2: VQC chain for 64 rows (16 lanes/row, 2 passes of 32 rows) ----
    {
        const int gidx = t >> 4;               // 0..31
        const int l    = t & 15;
        const int grp  = lane & 48;
        #pragma unroll 1
        for (int p2 = 0; p2 < 2; ++p2) {
            int rl = p2 * 32 + gidx;
            float gin[HID], h0v[HID];
            #pragma unroll
            for (int h = 0; h < HID; ++h) {
                gin[h] = ftanh(ghbuf[rl * 17 + h]     + cgin[h]);
                h0v[h] = ftanh(ghbuf[rl * 17 + 8 + h] + h0_b[h]);
            }
            float rz[4];
            #pragma unroll
            for (int q = 0; q < 4; ++q) {
                float a = crz_b[q];
                #pragma unroll
                for (int k = 0; k < 8; ++k) a = fmaf(gin[k], crz_w[q * 16 + k], a);
                #pragma unroll
                for (int k = 0; k < 8; ++k) a = fmaf(h0v[k], crz_w[q * 16 + 8 + k], a);
                rz[q] = ftanh(a) * PI_F;
            }
            float cq[4], sq[4];
            #pragma unroll
            for (int q = 0; q < 4; ++q) { cq[q] = __cosf(0.5f * rz[q]); sq[q] = __sinf(0.5f * rz[q]); }

            float er[4], ez[4];
            vqc_run(cq, sq, rotc + 0 * 32, l, grp, er);
            vqc_run(cq, sq, rotc + 1 * 32, l, grp, ez);

            float rr[HID], zz[HID];
            #pragma unroll
            for (int h = 0; h < HID; ++h) {
                float a = expand_b[h], b = expand_b[h];
                #pragma unroll
                for (int q = 0; q < 4; ++q) {
                    a = fmaf(er[q], expand_w[h * 4 + q], a);
                    b = fmaf(ez[q], expand_w[h * 4 + q], b);
                }
                rr[h] = sigm(a);
                zz[h] = sigm(b);
            }
            float ni[4];
            #pragma unroll
            for (int q = 0; q < 4; ++q) {
                float a = cn_b[q];
                #pragma unroll
                for (int k = 0; k < 8; ++k) a = fmaf(rr[k] * h0v[k], cn_w[q * 16 + k], a);
                #pragma unroll
                for (int k = 0; k < 8; ++k) a = fmaf(gin[k], cn_w[q * 16 + 8 + k], a);
                ni[q] = ftanh(a) * PI_F;
            }
            #pragma unroll
            for (int q = 0; q < 4; ++q) { cq[q] = __cosf(0.5f * ni[q]); sq[q] = __sinf(0.5f * ni[q]); }
            float en[4];
            vqc_run(cq, sq, rotc + 2 * 32, l, grp, en);

            float hn[HID];
            #pragma unroll
            for (int h = 0; h < HID; ++h) {
                float a = expand_b[h];
                #pragma unroll
                for (int q = 0; q < 4; ++q) a = fmaf(en[q], expand_w[h * 4 + q], a);
                float nn = ftanh(a);
                hn[h] = (1.f - zz[h]) * nn + zz[h] * h0v[h];
            }
            int pp = l;
            float a = mod_b[pp];
            #pragma unroll
            for (int h = 0; h < HID; ++h) a = fmaf(hn[h], mod_w[pp * 8 + h], a);
            modt[rl * 25 + pp] = ftanh(a);
            if (l < 8) {
                pp = l + 16;
                a = mod_b[pp];
                #pragma unroll
                for (int h = 0; h < HID; ++h) a = fmaf(hn[h], mod_w[pp * 8 + h], a);
                modt[rl * 25 + pp] = ftanh(a);
            }
        }
    }
    __syncthreads();

    // ---- phase 3: fuse interleaved T/S pairs with modulation, store ----
    const float alpha = sigm(fusion_alpha[0]);
    #pragma unroll
    for (int j = 0; j < 7; ++j) {
        int fi = wn + j * 4;
        if (fi >= 24) continue;                // gin/h0/pad frags
        float tb = trend_b[fi], sb = seasonal_b[fi];
        #pragma unroll
        for (int mf = 0; mf < 2; ++mf) {
            #pragma unroll
            for (int reg = 0; reg < 4; ++reg) {
                int rl = wm * 32 + mf * 16 + lg * 4 + reg;
                float v  = mf ? acc1[j][reg] : acc0[j][reg];
                float pt = __shfl_xor(v, 1, 64);
                float md = modt[rl * 25 + fi];
                if (!(lr & 1)) {               // even lane holds T, partner holds S
                    int R = b0 + rl;
                    if (R < Btot) {
                        float res = alpha * ((pt + sb) * (1.f + md)) + (1.f - alpha) * (v + tb);
                        out[(size_t)R * 192 + fi * 8 + (lr >> 1)] = res;
                    }
                }
            }
        }
    }
}

extern "C" void kernel_launch(void* const* d_in, const int* in_sizes, int n_in,
                              void* d_out, int out_size, void* d_ws, size_t ws_size,
                              hipStream_t stream) {
    const float* x          = (const float*)d_in[0];
    const float* decomp_w   = (const float*)d_in[1];
    const float* trend_w    = (const float*)d_in[2];
    const float* trend_b    = (const float*)d_in[3];
    const float* seasonal_w = (const float*)d_in[4];
    const float* seasonal_b = (const float*)d_in[5];
    const float* h0_w       = (const float*)d_in[6];
    const float* h0_b       = (const float*)d_in[7];
    const float* ta_w       = (const float*)d_in[8];
    const float* ta_b       = (const float*)d_in[9];
    const float* sc_w       = (const float*)d_in[10];
    const float* sc_b       = (const float*)d_in[11];
    const float* crz_w      = (const float*)d_in[12];
    const float* crz_b      = (const float*)d_in[13];
    const float* cn_w       = (const float*)d_in[14];
    const float* cn_b       = (const float*)d_in[15];
    const float* vqc_r      = (const float*)d_in[16];
    const float* vqc_u      = (const float*)d_in[17];
    const float* vqc_c      = (const float*)d_in[18];
    const float* expand_w   = (const float*)d_in[19];
    const float* expand_b   = (const float*)d_in[20];
    const float* mod_w      = (const float*)d_in[21];
    const float* mod_b      = (const float*)d_in[22];
    const float* fus_a      = (const float*)d_in[23];
    float* out = (float*)d_out;

    float* ws   = (float*)d_ws;
    float* dw   = ws + WS_DW;
    float* rotc = ws + WS_ROTC;
    float* cgin = ws + WS_CGIN;
    float* Wt   = ws + WS_WT;
    unsigned char* img = (unsigned char*)d_ws + WS_IMG_BYTE;

    const int Btot = in_sizes[0] / (SEQ * NF);

    k_setup<<<1, 256, 0, stream>>>(decomp_w, vqc_r, vqc_u, vqc_c, sc_w, sc_b, ta_b,
                                   dw, rotc, cgin);
    k_compose<<<(SEQ * 640 + 255) / 256, 256, 0, stream>>>(dw, trend_w, seasonal_w, ta_w, Wt);
    k_img<<<(NCH * NCOLI * 64 + 255) / 256, 256, 0, stream>>>(Wt, sc_w, h0_w, img);

    k_fused<<<(Btot + 63) / 64, 512, 0, stream>>>(x, img, rotc, cgin, h0_b,
                                                  crz_w, crz_b, cn_w, cn_b,
                                                  expand_w, expand_b, mod_w, mod_b,
                                                  trend_b, seasonal_b, fus_a, out, Btot);
}

// Round 6
// 65.671 us; speedup vs baseline: 2.3448x; 1.2015x over previous
//
#include <hip/hip_runtime.h>
#include <hip/hip_bf16.h>
#include <cmath>

#define SEQ   168
#define NF    8
#define PRED  24
#define HID   8
#define KTOT  1344          // SEQ*NF (x row flat length)
#define NSCH  6             // s-chunks
#define SCH   32            // s per chunk (padded K = 192)
#define BCHB  32768         // B image bytes per chunk: TS 24576 + GH 8192
#define PI_F  3.14159265358979323846f

// ---------------- workspace layout ----------------
#define WS_DW       0        // floats: 8*25 softmaxed decomp weights
#define WS_ROTC     256      // floats: 3*2*4*4 rot coeffs
#define WS_CGIN     512      // floats: 8 gin constants
#define WS_WT       1024     // floats: 168*640 composed weights, ends 108544
#define WS_IMG_BYTE 524288   // bytes: bf16 image 6*32768 = 196608

typedef __attribute__((ext_vector_type(8))) short bf16x8;
typedef __attribute__((ext_vector_type(4))) float f32x4;

__device__ __forceinline__ float frcp(float x)  { return __builtin_amdgcn_rcpf(x); }
__device__ __forceinline__ float ftanh(float x) {
    float xc = fminf(fmaxf(x, -15.f), 15.f);
    float e  = __expf(2.f * xc);
    return (e - 1.f) * frcp(e + 1.f);
}
__device__ __forceinline__ float sigm(float x) { return frcp(1.f + __expf(-x)); }
__device__ __forceinline__ unsigned short f2bf(float f) {
    __hip_bfloat16 h = __float2bfloat16(f);
    return __builtin_bit_cast(unsigned short, h);
}
__device__ __forceinline__ unsigned pack2(float a, float b) {
    return (unsigned)f2bf(a) | ((unsigned)f2bf(b) << 16);
}
// async global->LDS, 16B per lane; lds dest = wave-uniform base + lane*16
__device__ __forceinline__ void gload16(const void* g, void* l) {
    __builtin_amdgcn_global_load_lds(
        (const __attribute__((address_space(1))) unsigned int*)g,
        (__attribute__((address_space(3))) unsigned int*)l, 16, 0, 0);
}

// ---------------- setup: softmax(dw) + rot coeffs + gin consts ----------------
__global__ void k_setup(const float* __restrict__ decomp_w,
                        const float* __restrict__ vr, const float* __restrict__ vu,
                        const float* __restrict__ vc,
                        const float* __restrict__ sc_w, const float* __restrict__ sc_b,
                        const float* __restrict__ ta_b,
                        float* __restrict__ dw, float* __restrict__ rotc,
                        float* __restrict__ cgin) {
    int t = threadIdx.x;
    if (t < 8) {
        const float* row = decomp_w + t * 25;
        float m = row[0];
        for (int k = 1; k < 25; ++k) m = fmaxf(m, row[k]);
        float e[25]; float sum = 0.f;
        for (int k = 0; k < 25; ++k) { e[k] = expf(row[k] - m); sum += e[k]; }
        float inv = 1.f / sum;
        for (int k = 0; k < 25; ++k) dw[t * 25 + k] = e[k] * inv;
    } else if (t >= 64 && t < 88) {
        int n = t - 64;
        int v = n / 8, rest = n % 8;
        const float* w = (v == 0 ? vr : (v == 1 ? vu : vc)) + rest * 3;
        float phi = w[0], th = w[1], om = w[2];
        float c = cosf(0.5f * th), s = sinf(0.5f * th);
        float ap = -0.5f * (phi + om);
        float am =  0.5f * (phi - om);
        float* o = rotc + n * 4;
        o[0] = cosf(ap) * c;
        o[1] = sinf(ap) * c;
        o[2] = cosf(am) * s;
        o[3] = sinf(am) * s;
    } else if (t >= 96 && t < 104) {
        int h = t - 96;
        float a = sc_b[h];
        for (int cc = 0; cc < 32; ++cc) {
            float s = 0.f;
            for (int f = 0; f < 8; ++f) s += sc_w[h * 256 + f * 32 + cc];
            a = fmaf(ta_b[cc], s, a);
        }
        cgin[h] = a;
    }
}

// ---------------- compose conv into projection weights (f32, verified r1-r5) ----------------
// Wt cols: 0-191 trend (p*8+f), 192-383 seasonal, 384-639 ctx ((48+cc)*8+f)
__global__ void k_compose(const float* __restrict__ dw,
                          const float* __restrict__ trend_w,
                          const float* __restrict__ seasonal_w,
                          const float* __restrict__ ta_w,
                          float* __restrict__ Wt) {
    int n = blockIdx.x * 256 + threadIdx.x;
    if (n >= SEQ * 640) return;
    int sx  = n / 640;
    int col = n % 640;
    int j = col >> 3;
    int f = col & 7;
    const float* dwf = dw + f * 25;
    const float* wsel;
    int isTrend = 0;
    if (j < 24)      { wsel = trend_w    + j        * SEQ; isTrend = 1; }
    else if (j < 48) { wsel = seasonal_w + (j - 24) * SEQ; }
    else             { wsel = ta_w       + (j - 48) * SEQ; }
    float acc = 0.f;
    if (sx == 0) {
        for (int s = 0; s <= 12; ++s) {
            float cw = 0.f;
            for (int k = 0; k <= 12 - s; ++k) cw += dwf[k];
            acc = fmaf(cw, wsel[s], acc);
        }
    } else if (sx == 167) {
        for (int s = 155; s < 168; ++s) {
            float cw = 0.f;
            for (int k = 179 - s; k < 25; ++k) cw += dwf[k];
            acc = fmaf(cw, wsel[s], acc);
        }
    } else {
        int lo = sx - 12; if (lo < 0) lo = 0;
        int hi = sx + 12; if (hi > 167) hi = 167;
        for (int s = lo; s <= hi; ++s) acc = fmaf(dwf[sx - s + 12], wsel[s], acc);
    }
    Wt[sx * 640 + col] = isTrend ? acc : (wsel[sx] - acc);
}

// ---------------- build pre-swizzled per-feature bf16 B image ----------------
// per chunk (32768 B): TS [f][48 c][32 s] at f*3072, byte (c*64+s*2)^((c&7)<<4)
//                      GH [f][16 c][32 s] at 24576+f*1024, same swizzle
// TS col c: p=c>>1, ts=c&1 -> Wt[s*640 + ts*192 + p*8 + f]
// GH col c<8: gin h=c (sc_w folded per feature); c>=8: h0 col h=c-8 (f==7 lags)
__global__ void k_img(const float* __restrict__ Wt, const float* __restrict__ sc_w,
                      const float* __restrict__ h0_w, unsigned char* __restrict__ imgb) {
    int idx = blockIdx.x * 256 + threadIdx.x;   // 6*16384 shorts
    if (idx >= NSCH * 16384) return;
    int kc = idx / 16384;
    int r  = idx % 16384;
    float val = 0.f;
    int dest;
    if (r < 12288) {
        int f  = r / 1536;
        int r2 = r % 1536;
        int c  = r2 / 32;
        int sl = r2 % 32;
        int s  = kc * SCH + sl;
        if (s < SEQ) {
            int p = c >> 1, ts = c & 1;
            val = Wt[s * 640 + ts * 192 + p * 8 + f];
        }
        dest = f * 3072 + ((c * 64 + sl * 2) ^ ((c & 7) << 4));
    } else {
        int r2 = r - 12288;
        int f  = r2 / 512;
        int r3 = r2 % 512;
        int c  = r3 / 32;
        int sl = r3 % 32;
        int s  = kc * SCH + sl;
        if (s < SEQ) {
            if (c < 8) {
                float a = 0.f;
                for (int cc = 0; cc < 32; ++cc)
                    a = fmaf(sc_w[c * 256 + f * 32 + cc], Wt[s * 640 + 384 + cc * 8 + f], a);
                val = a;
            } else if (f == 7) {
                const int LIDX[11] = {167,166,165,164,163,162,145,144,143,1,0};
                #pragma unroll
                for (int i = 0; i < 11; ++i)
                    if (s == LIDX[i]) val = h0_w[(c - 8) * 11 + i];
            }
        }
        dest = 24576 + f * 1024 + ((c * 64 + sl * 2) ^ ((c & 7) << 4));
    }
    *(unsigned short*)(imgb + (size_t)kc * BCHB + dest) = f2bf(val);
}

// ---------------- VQC: 16 lanes hold the 16 complex amplitudes (verified) ----------------
__device__ __forceinline__ float shflg(float v, int grp, int idx) {
    return __shfl(v, grp + idx, 64);
}

__device__ void vqc_run(const float cq[4], const float sq[4],
                        const float* __restrict__ rc,
                        int l, int grp, float exps[4]) {
    float re = (l == 0) ? 1.f : 0.f;
    float im = 0.f;
    #pragma unroll
    for (int layer = 0; layer < 2; ++layer) {
        #pragma unroll
        for (int q = 0; q < 4; ++q) {
            int m = 1 << (3 - q);
            float pre = shflg(re, grp, l ^ m);
            float pim = shflg(im, grp, l ^ m);
            float sg = (l & m) ? sq[q] : -sq[q];
            re = cq[q] * re + sg * pre;
            im = cq[q] * im + sg * pim;
        }
        #pragma unroll
        for (int q = 0; q < 4; ++q) {
            int m = 1 << (3 - q);
            const float* g = rc + (layer * 4 + q) * 4;
            float A = g[0], B = g[1], C = g[2], D = g[3];
            float pre = shflg(re, grp, l ^ m);
            float pim = shflg(im, grp, l ^ m);
            float car, cai, cpr, cpi;
            if (l & m) { car = A; cai = -B; cpr =  C; cpi = -D; }
            else       { car = A; cai =  B; cpr = -C; cpi = -D; }
            float nre = car * re - cai * im + cpr * pre - cpi * pim;
            float nim = car * im + cai * re + cpr * pim + cpi * pre;
            re = nre; im = nim;
        }
        #pragma unroll
        for (int q = 0; q < 4; ++q) {
            int mc = 1 << (3 - q);
            int mt = 1 << (3 - ((q + 1) & 3));
            float pre = shflg(re, grp, l ^ mt);
            float pim = shflg(im, grp, l ^ mt);
            if (l & mc) { re = pre; im = pim; }
        }
    }
    float prob = re * re + im * im;
    float v0 = (l & 8) ? -prob : prob;
    float v1 = (l & 4) ? -prob : prob;
    float v2 = (l & 2) ? -prob : prob;
    float v3 = (l & 1) ? -prob : prob;
    #pragma unroll
    for (int m = 1; m < 16; m <<= 1) {
        v0 += __shfl_xor(v0, m, 64);
        v1 += __shfl_xor(v1, m, 64);
        v2 += __shfl_xor(v2, m, 64);
        v3 += __shfl_xor(v3, m, 64);
    }
    exps[0] = v0; exps[1] = v1; exps[2] = v2; exps[3] = v3;
}

// ---------------- mega-fused: per-feature GEMMs + VQC + fusion + store ----------------
// M-tile 32, 8 waves = 2(M: wm) x 4(N: wn); frag fi = wn + 4j; fi<24: f=fi/3, jj=fi%3;
// fi>=24: gin/h0 partial over features {2wn, 2wn+1}, cross-wave summed in epilogue.
__global__ __launch_bounds__(512, 4)
void k_fused(const float* __restrict__ x, const unsigned char* __restrict__ img,
             const float* __restrict__ rotc, const float* __restrict__ cgin,
             const float* __restrict__ h0_b,
             const float* __restrict__ crz_w, const float* __restrict__ crz_b,
             const float* __restrict__ cn_w, const float* __restrict__ cn_b,
             const float* __restrict__ expand_w, const float* __restrict__ expand_b,
             const float* __restrict__ mod_w, const float* __restrict__ mod_b,
             const float* __restrict__ trend_b, const float* __restrict__ seasonal_b,
             const float* __restrict__ fusion_alpha,
             float* __restrict__ out, int Btot)
{
    __shared__ uint4 ldsq[3072];                 // 49152 B
    unsigned char* Asb = (unsigned char*)ldsq;   // 16 KB: [f][32 row][32 s], swizzled
    unsigned char* Bsb = (unsigned char*)ldsq + 16384; // 32 KB image chunk (pre-swizzled)
    float* ghpart = (float*)ldsq;                        // epi: [4 wn][32 row][16] = 8 KB
    float* ghbuf  = (float*)((unsigned char*)ldsq + 16384); // epi: [32][17]
    float* modt   = (float*)((unsigned char*)ldsq + 20480); // epi: [32][25]

    const int t    = threadIdx.x;
    const int b0   = blockIdx.x * 32;
    const int w    = t >> 6, lane = t & 63, lr = lane & 15, lg = lane >> 4;
    const int wm   = w & 1, wn = w >> 1;

    f32x4 acc[7];
    #pragma unroll
    for (int j = 0; j < 7; ++j) acc[j] = (f32x4){0.f, 0.f, 0.f, 0.f};

    // A staging: thread covers (row = t>>4, s-pair = t&15) -> 16 floats = 2 s x 8 f
    const int arow  = t >> 4;
    const int spair = t & 15;
    int gr = b0 + arow; if (gr >= Btot) gr = Btot - 1;
    const float* xrow = x + (size_t)gr * KTOT;

    float4 ra[4];
    {
        int off = spair * 16; if (off > 1328) off = 1328;   // kc=0 never clamps
        #pragma unroll
        for (int u = 0; u < 4; ++u) ra[u] = *(const float4*)&xrow[off + u * 4];
    }

    for (int kc = 0; kc < NSCH; ++kc) {
        __syncthreads();                       // prev tile fully consumed
        // publish A: transpose (2 s x 8 f) -> per-feature planes [row][s]
        {
            const float* rf = (const float*)ra;           // 16 floats, k = ds*8+f
            int wb  = arow * 64 + spair * 4;
            int swz = (arow & 7) << 4;
            #pragma unroll
            for (int f = 0; f < 8; ++f)
                *(unsigned*)&Asb[(f * 2048 + wb) ^ swz] = pack2(rf[f], rf[8 + f]);
        }
        // B: async DMA chunk (linear; image pre-swizzled)
        {
            const unsigned char* bsrc = img + (size_t)kc * BCHB + w * 1024 + (lane << 4);
            unsigned char* bdst = Bsb + w * 1024;
            #pragma unroll
            for (int i = 0; i < 4; ++i)
                gload16(bsrc + i * 8192, bdst + i * 8192);
        }
        __syncthreads();                       // drains DMA + ds_writes; tile visible
        if (kc + 1 < NSCH) {                   // A prefetch (lands during compute)
            int off = (kc + 1) * 256 + spair * 16; if (off > 1328) off = 1328;
            #pragma unroll
            for (int u = 0; u < 4; ++u) ra[u] = *(const float4*)&xrow[off + u * 4];
        }
        // compute: 6 TS frags + gh (2 feature sub-steps)
        const int m = wm * 16 + lr;
        const int aswz = (m & 7) << 4;
        #pragma unroll
        for (int j = 0; j < 6; ++j) {
            int fi = wn + 4 * j;
            int f  = fi / 3;
            int jj = fi - f * 3;
            bf16x8 av = *(const bf16x8*)&Asb[(f * 2048 + m * 64 + lg * 16) ^ aswz];
            int c = jj * 16 + lr;
            bf16x8 bv = *(const bf16x8*)&Bsb[f * 3072 + ((c * 64 + lg * 16) ^ ((c & 7) << 4))];
            acc[j] = __builtin_amdgcn_mfma_f32_16x16x32_bf16(av, bv, acc[j], 0, 0, 0);
        }
        #pragma unroll
        for (int g = 0; g < 2; ++g) {
            int f = wn * 2 + g;
            bf16x8 av = *(const bf16x8*)&Asb[(f * 2048 + m * 64 + lg * 16) ^ aswz];
            bf16x8 bv = *(const bf16x8*)&Bsb[24576 + f * 1024 + ((lr * 64 + lg * 16) ^ ((lr & 7) << 4))];
            acc[6] = __builtin_amdgcn_mfma_f32_16x16x32_bf16(av, bv, acc[6], 0, 0, 0);
        }
    }
    __syncthreads();

    // ---- epi 1: publish gh partials (per wn), then cross-wave sum ----
    #pragma unroll
    for (int reg = 0; reg < 4; ++reg)
        ghpart[(wn * 32 + wm * 16 + lg * 4 + reg) * 16 + lr] = acc[6][reg];
    __syncthreads();
    {
        int row = t >> 4, col = t & 15;
        float s = ghpart[row * 16 + col] + ghpart[(32 + row) * 16 + col]
                + ghpart[(64 + row) * 16 + col] + ghpart[(96 + row) * 16 + col];
        ghbuf[row * 17 + col] = s;
    }
    __syncthreads();

    // ---- epi 2: VQC chain, 32 rows in one pass (16 lanes/row) ----
    {
        const int rl  = t >> 4;
        const int l   = t & 15;
        const int grp = lane & 48;
        float gin[HID], h0v[HID];
        #pragma unroll
        for (int h = 0; h < HID; ++h) {
            gin[h] = ftanh(ghbuf[rl * 17 + h]     + cgin[h]);
            h0v[h] = ftanh(ghbuf[rl * 17 + 8 + h] + h0_b[h]);
        }
        float rz[4];
        #pragma unroll
        for (int q = 0; q < 4; ++q) {
            float a = crz_b[q];
            #pragma unroll
            for (int k = 0; k < 8; ++k) a = fmaf(gin[k], crz_w[q * 16 + k], a);
            #pragma unroll
            for (int k = 0; k < 8; ++k) a = fmaf(h0v[k], crz_w[q * 16 + 8 + k], a);
            rz[q] = ftanh(a) * PI_F;
        }
        float cq[4], sq[4];
        #pragma unroll
        for (int q = 0; q < 4; ++q) { cq[q] = __cosf(0.5f * rz[q]); sq[q] = __sinf(0.5f * rz[q]); }

        float er[4], ez[4];
        vqc_run(cq, sq, rotc + 0 * 32, l, grp, er);
        vqc_run(cq, sq, rotc + 1 * 32, l, grp, ez);

        float rr[HID], zz[HID];
        #pragma unroll
        for (int h = 0; h < HID; ++h) {
            float a = expand_b[h], b = expand_b[h];
            #pragma unroll
            for (int q = 0; q < 4; ++q) {
                a = fmaf(er[q], expand_w[h * 4 + q], a);
                b = fmaf(ez[q], expand_w[h * 4 + q], b);
            }
            rr[h] = sigm(a);
            zz[h] = sigm(b);
        }
        float ni[4];
        #pragma unroll
        for (int q = 0; q < 4; ++q) {
            float a = cn_b[q];
            #pragma unroll
            for (int k = 0; k < 8; ++k) a = fmaf(rr[k] * h0v[k], cn_w[q * 16 + k], a);
            #pragma unroll
            for (int k = 0; k < 8; ++k) a = fmaf(gin[k], cn_w[q * 16 + 8 + k], a);
            ni[q] = ftanh(a) * PI_F;
        }
        #pragma unroll
        for (int q = 0; q < 4; ++q) { cq[q] = __cosf(0.5f * ni[q]); sq[q] = __sinf(0.5f * ni[q]); }
        float en[4];
        vqc_run(cq, sq, rotc + 2 * 32, l, grp, en);

        float hn[HID];
        #pragma unroll
        for (int h = 0; h < HID; ++h) {
            float a = expand_b[h];
            #pragma unroll
            for (int q = 0; q < 4; ++q) a = fmaf(en[q], expand_w[h * 4 + q], a);
            float nn = ftanh(a);
            hn[h] = (1.f - zz[h]) * nn + zz[h] * h0v[h];
        }
        int pp = l;
        float a = mod_b[pp];
        #pragma unroll
        for (int h = 0; h < HID; ++h) a = fmaf(hn[h], mod_w[pp * 8 + h], a);
        modt[rl * 25 + pp] = ftanh(a);
        if (l < 8) {
            pp = l + 16;
            a = mod_b[pp];
            #pragma unroll
            for (int h = 0; h < HID; ++h) a = fmaf(hn[h], mod_w[pp * 8 + h], a);
            modt[rl * 25 + pp] = ftanh(a);
        }
    }
    __syncthreads();

    // ---- epi 3: fuse interleaved T/S pairs with modulation, store ----
    const float alpha = sigm(fusion_alpha[0]);
    #pragma unroll
    for (int j = 0; j < 6; ++j) {
        int fi = wn + 4 * j;
        int f  = fi / 3;
        int jj = fi - f * 3;
        int p  = jj * 8 + (lr >> 1);
        #pragma unroll
        for (int reg = 0; reg < 4; ++reg) {
            int rl = wm * 16 + lg * 4 + reg;
            float v  = acc[j][reg];
            float pt = __shfl_xor(v, 1, 64);
            if (!(lr & 1)) {                   // even lane: T; partner lane: S
                int R = b0 + rl;
                if (R < Btot) {
                    float md = modt[rl * 25 + p];
                    float res = alpha * ((pt + seasonal_b[p]) * (1.f + md))
                              + (1.f - alpha) * (v + trend_b[p]);
                    out[(size_t)R * 192 + p * 8 + f] = res;
                }
            }
        }
    }
}

extern "C" void kernel_launch(void* const* d_in, const int* in_sizes, int n_in,
                              void* d_out, int out_size, void* d_ws, size_t ws_size,
                              hipStream_t stream) {
    const float* x          = (const float*)d_in[0];
    const float* decomp_w   = (const float*)d_in[1];
    const float* trend_w    = (const float*)d_in[2];
    const float* trend_b    = (const float*)d_in[3];
    const float* seasonal_w = (const float*)d_in[4];
    const float* seasonal_b = (const float*)d_in[5];
    const float* h0_w       = (const float*)d_in[6];
    const float* h0_b       = (const float*)d_in[7];
    const float* ta_w       = (const float*)d_in[8];
    const float* ta_b       = (const float*)d_in[9];
    const float* sc_w       = (const float*)d_in[10];
    const float* sc_b       = (const float*)d_in[11];
    const float* crz_w      = (const float*)d_in[12];
    const float* crz_b      = (const float*)d_in[13];
    const float* cn_w       = (const float*)d_in[14];
    const float* cn_b       = (const float*)d_in[15];
    const float* vqc_r      = (const float*)d_in[16];
    const float* vqc_u      = (const float*)d_in[17];
    const float* vqc_c      = (const float*)d_in[18];
    const float* expand_w   = (const float*)d_in[19];
    const float* expand_b   = (const float*)d_in[20];
    const float* mod_w      = (const float*)d_in[21];
    const float* mod_b      = (const float*)d_in[22];
    const float* fus_a      = (const float*)d_in[23];
    float* out = (float*)d_out;

    float* ws   = (float*)d_ws;
    float* dw   = ws + WS_DW;
    float* rotc = ws + WS_ROTC;
    float* cgin = ws + WS_CGIN;
    float* Wt   = ws + WS_WT;
    unsigned char* img = (unsigned char*)d_ws + WS_IMG_BYTE;

    const int Btot = in_sizes[0] / (SEQ * NF);

    k_setup<<<1, 256, 0, stream>>>(decomp_w, vqc_r, vqc_u, vqc_c, sc_w, sc_b, ta_b,
                                   dw, rotc, cgin);
    k_compose<<<(SEQ * 640 + 255) / 256, 256, 0, stream>>>(dw, trend_w, seasonal_w, ta_w, Wt);
    k_img<<<(NSCH * 16384 + 255) / 256, 256, 0, stream>>>(Wt, sc_w, h0_w, img);

    k_fused<<<(Btot + 31) / 32, 512, 0, stream>>>(x, img, rotc, cgin, h0_b,
                                                  crz_w, crz_b, cn_w, cn_b,
                                                  expand_w, expand_b, mod_w, mod_b,
                                                  trend_b, seasonal_b, fus_a, out, Btot);
}